// Round 23
// baseline (224.269 us; speedup 1.0000x reference)
//
#include <hip/hip_runtime.h>
#include <hip/hip_bf16.h>

#define FEATN 898
#define EMBD 128
#define KT_FULL 28          // 28 full k-tiles of 32 (896); tile 28 (k=896..897) on register path
#define KT_ALL 29           // padded tiles in Wfrag
#define CH 2                // k-tiles per async-staged chunk (64 f32 cols)
#define NCHUNK 14           // KT_FULL / CH
#define CBITS 8
#define CSZ 256             // nodes per coarse bucket
#define CAP2 12288          // per-bucket capacity (mean ~8183, +45 sigma)
#define EPB 4096            // edges per p1 block

typedef __bf16 bf16x8 __attribute__((ext_vector_type(8)));
typedef float f32x4 __attribute__((ext_vector_type(4)));
typedef unsigned short ushort8 __attribute__((ext_vector_type(8)));

__device__ inline unsigned short f2bf(float f) {
    unsigned int u = __float_as_uint(f);
    unsigned int r = u + 0x7fffu + ((u >> 16) & 1u);   // RNE
    return (unsigned short)(r >> 16);
}
__device__ inline float bflo(unsigned int u) {
    return __uint_as_float(u << 16);
}
__device__ inline float bfhi(unsigned int u) {
    return __uint_as_float(u & 0xFFFF0000u);
}
__device__ inline unsigned int pk_bf2(float a, float b) {
    __hip_bfloat162 h = __float22bfloat162_rn(make_float2(a, b));
    unsigned int r;
    __builtin_memcpy(&r, &h, 4);
    return r;
}
// async global->LDS DMA, 16B/lane: dest = lds base (wave-uniform) + lane*16; src per-lane
__device__ inline void gl16(const void* g, void* l) {
    __builtin_amdgcn_global_load_lds((const __attribute__((address_space(1))) unsigned int*)g,
                                     (__attribute__((address_space(3))) unsigned int*)l,
                                     16, 0, 0);
}

// ---------------- p1 + valprep merged: blocks [0,nbp1) sort edges; rest do valv/Wf prep ----------------
__global__ __launch_bounds__(256) void k_p1v(const int* __restrict__ ei, int E, int N, int nbp1, int nbv,
                                             int* __restrict__ gtails, unsigned int* __restrict__ bb,
                                             const float* __restrict__ x, const float* __restrict__ emb,
                                             float* __restrict__ valv,
                                             const float* __restrict__ W1, unsigned short* __restrict__ Wf) {
    int t = threadIdx.x;
    if ((int)blockIdx.x >= nbp1) {
        int vb = (int)blockIdx.x - nbp1;
        if (vb < nbv) {                           // valv: feat[i][0] = emb[poi[i>>7]][i&127]
            int i = vb * 256 + t;
            if (i < N) {
                int r = i >> 7;
                int poi = (int)x[(size_t)r * FEATN];
                poi = min(max(poi, 0), N - 1);
                valv[i] = emb[(size_t)poi * EMBD + (i & 127)];
            }
        } else {                                   // Wfrag prep
            int id = (vb - nbv) * 256 + t;
            if (id < KT_ALL * 4 * 64 * 8) {
                int e = id & 7;
                int l = (id >> 3) & 63;
                int nt = (id >> 9) & 3;
                int kt = id >> 11;
                int k = kt * 32 + (l >> 4) * 8 + e;
                int n = nt * 16 + (l & 15);
                float v = (k < FEATN) ? W1[(size_t)k * 64 + n] : 0.f;
                Wf[id] = f2bf(v);
            }
        }
        return;
    }
    // ---- p1 body: in-LDS counting sort per block -> coalesced global runs ----
    __shared__ unsigned int stash[EPB];       // 16 KB, sorted by bucket
    __shared__ int hist[256], loff[256], gbase[256], lcur[256], sc[256];
    __shared__ int anyf;
    hist[t] = 0;
    if (t == 0) anyf = 0;
    __syncthreads();
    if (ei[2 * t + 1] != 0) atomicOr(&anyf, 1);   // int64 layout => hi words all zero
    __syncthreads();
    int f = anyf;                                  // 1 = int32 layout, 0 = int64 lo/hi pairs
    int e0 = blockIdx.x * EPB;
#pragma unroll
    for (int i = 0; i < EPB / 256; ++i) {
        int e = e0 + i * 256 + t;
        if (e < E) {
            int d = f ? ei[(size_t)E + e] : ei[2 * ((size_t)E + e)];
            d = min(max(d, 0), N - 1);
            atomicAdd(&hist[d >> CBITS], 1);
        }
    }
    __syncthreads();
    int v = hist[t];
    sc[t] = v;
    __syncthreads();
    for (int o = 1; o < 256; o <<= 1) {
        int x_ = (t >= o) ? sc[t - o] : 0;
        __syncthreads();
        sc[t] += x_;
        __syncthreads();
    }
    loff[t] = sc[t] - v;
    lcur[t] = sc[t] - v;
    gbase[t] = (v > 0) ? atomicAdd(&gtails[t], v) : 0;
    __syncthreads();
#pragma unroll
    for (int i = 0; i < EPB / 256; ++i) {
        int e = e0 + i * 256 + t;
        if (e < E) {
            int s_ = f ? ei[e] : ei[2 * (size_t)e];
            int d = f ? ei[(size_t)E + e] : ei[2 * ((size_t)E + e)];
            s_ = min(max(s_, 0), N - 1);
            d = min(max(d, 0), N - 1);
            int p = atomicAdd(&lcur[d >> CBITS], 1);
            stash[p] = ((unsigned)s_ << 16) | (unsigned)d;
        }
    }
    __syncthreads();
    int T = min(EPB, E - e0);
    for (int i = t; i < T; i += 256) {
        unsigned int u = stash[i];
        int d = (int)(u & 0xFFFFu);
        int c = d >> CBITS;
        int pos = gbase[c] + (i - loff[c]);
        if (pos < CAP2)
            bb[(size_t)c * CAP2 + pos] = ((u >> 16) << CBITS) | (unsigned)(d & (CSZ - 1));
    }
}

// ---------------- p2 (+inline bucket-offset scan): per-bucket CSR build in LDS ----------------
__global__ __launch_bounds__(256) void k_p2(const unsigned int* __restrict__ bb,
                                            const int* __restrict__ gtails, int nbc,
                                            int N, int* __restrict__ rowoff, float* __restrict__ dinv,
                                            int* __restrict__ colidx) {
    __shared__ unsigned int stash[CAP2];     // 48 KB
    __shared__ int hist[CSZ], curs[CSZ], sc[CSZ], tta[CSZ];
    int b = blockIdx.x;
    int t = threadIdx.x;
    int tot = 0;
    if (t < nbc) tot = min(gtails[t], CAP2) + min(CSZ, N - t * CSZ);
    tta[t] = tot;
    sc[t] = tot;
    __syncthreads();
    for (int o = 1; o < 256; o <<= 1) {
        int x_ = (t >= o) ? sc[t - o] : 0;
        __syncthreads();
        sc[t] += x_;
        __syncthreads();
    }
    if (b == nbc - 1 && t == 0) rowoff[N] = sc[nbc - 1];   // grand total
    int base = sc[b] - tta[b];
    __syncthreads();
    int node0 = b * CSZ;
    int nbn = min(CSZ, N - node0);
    int T = min(gtails[b], CAP2);
    hist[t] = 0;
    __syncthreads();
    for (int i = t; i < T; i += 256) {
        unsigned int u = bb[(size_t)b * CAP2 + i];
        stash[i] = u;
        atomicAdd(&hist[u & (CSZ - 1)], 1);
    }
    __syncthreads();
    int v = (t < nbn) ? hist[t] + 1 : 0;
    sc[t] = v;
    __syncthreads();
    for (int o = 1; o < 256; o <<= 1) {
        int x_ = (t >= o) ? sc[t - o] : 0;
        __syncthreads();
        sc[t] += x_;
        __syncthreads();
    }
    if (t < nbn) {
        int node = node0 + t;
        int ex = sc[t] - v;
        rowoff[node] = base + ex;
        dinv[node] = rsqrtf((float)(hist[t] + 1));
        colidx[base + ex] = node;            // self loop first
        curs[t] = ex + 1;
    }
    __syncthreads();
    for (int i = t; i < T; i += 256) {
        unsigned int u = stash[i];
        int slot = atomicAdd(&curs[u & (CSZ - 1)], 1);
        colidx[base + slot] = (int)(u >> CBITS);
    }
}

// ---------------- GEMM1 via MFMA: row-major-linear x staging (4 segments/DMA), dbuf ----------------
__global__ __launch_bounds__(256, 3) void k_gemm1m(const float* __restrict__ x,
                                                   const unsigned short* __restrict__ Wf,
                                                   const float* __restrict__ W1,
                                                   const float* __restrict__ valv,
                                                   const float* __restrict__ dinv, int N,
                                                   unsigned short* __restrict__ out) {
    __shared__ float xl[2][64 * 64];           // [buf][row*64 + col]  32 KB
    __shared__ ushort8 wlds[2][CH * 4 * 64];   // [buf][granule]       16 KB
    int t = threadIdx.x;
    int w = t >> 6;
    int l = t & 63;
    int r0 = blockIdx.x * 64;
    int kg = l >> 4;
    const ushort8* wfg = (const ushort8*)Wf;

    auto STAGE = [&](int c, int buf) {
        int c64 = c * 64;
#pragma unroll
        for (int p = 0; p < 4; ++p) {
            int rr = w * 16 + p * 4 + (l >> 4);
            int rg = r0 + rr;
            if (rg >= N) rg = N - 1;
            gl16(x + (size_t)rg * FEATN + c64 + (l & 15) * 4, &xl[buf][(w * 16 + p * 4) * 64]);
        }
#pragma unroll
        for (int q = 0; q < 2; ++q) {
            int blkg = w * 2 + q;
            gl16(&wfg[(size_t)c * 512 + blkg * 64 + l], &wlds[buf][blkg * 64]);
        }
    };

    f32x4 acc[4];
#pragma unroll
    for (int nt = 0; nt < 4; ++nt) acc[nt] = (f32x4){0.f, 0.f, 0.f, 0.f};

    STAGE(0, 0);
    __syncthreads();
    for (int c = 0; c < NCHUNK; ++c) {
        int buf = c & 1;
        if (c + 1 < NCHUNK) STAGE(c + 1, buf ^ 1);
#pragma unroll
        for (int kt = 0; kt < CH; ++kt) {
            const float* xr = &xl[buf][(w * 16 + (l & 15)) * 64 + kt * 32 + kg * 8];
            f32x4 lo = *(const f32x4*)xr;
            f32x4 hi = *(const f32x4*)(xr + 4);
            if (c == 0 && kt == 0 && kg == 0) lo.x = 0.f;   // zero POI-id col
            ushort8 u;
            unsigned int p0 = pk_bf2(lo.x, lo.y), p1 = pk_bf2(lo.z, lo.w);
            unsigned int p2 = pk_bf2(hi.x, hi.y), p3 = pk_bf2(hi.z, hi.w);
            u[0] = (unsigned short)p0; u[1] = (unsigned short)(p0 >> 16);
            u[2] = (unsigned short)p1; u[3] = (unsigned short)(p1 >> 16);
            u[4] = (unsigned short)p2; u[5] = (unsigned short)(p2 >> 16);
            u[6] = (unsigned short)p3; u[7] = (unsigned short)(p3 >> 16);
            bf16x8 a;
            __builtin_memcpy(&a, &u, 16);
#pragma unroll
            for (int nt = 0; nt < 4; ++nt) {
                bf16x8 b;
                ushort8 ub = wlds[buf][(kt * 4 + nt) * 64 + l];
                __builtin_memcpy(&b, &ub, 16);
                acc[nt] = __builtin_amdgcn_mfma_f32_16x16x32_bf16(a, b, acc[nt], 0, 0, 0);
            }
        }
        __syncthreads();
    }
    {   // tail k-tile (k=896..897)
        int rA = r0 + w * 16 + (l & 15);
        int rC = (rA < N) ? rA : (N - 1);
        ushort8 u = (ushort8)0;
        if (kg == 0) {
            float2 q = *(const float2*)(x + (size_t)rC * FEATN + 896);
            u[0] = f2bf(q.x);
            u[1] = f2bf(q.y);
        }
        bf16x8 a;
        __builtin_memcpy(&a, &u, 16);
#pragma unroll
        for (int nt = 0; nt < 4; ++nt) {
            bf16x8 b;
            ushort8 ub = wfg[(KT_FULL * 4 + nt) * 64 + l];
            __builtin_memcpy(&b, &ub, 16);
            acc[nt] = __builtin_amdgcn_mfma_f32_16x16x32_bf16(a, b, acc[nt], 0, 0, 0);
        }
    }

    int colb = l & 15;
    int rquad = l >> 4;
    int rowbase = r0 + w * 16 + rquad * 4;
    float dv[4], vv[4];
#pragma unroll
    for (int rg = 0; rg < 4; ++rg) {
        int row = rowbase + rg;
        int rc = (row < N) ? row : (N - 1);
        dv[rg] = dinv[rc];
        vv[rg] = valv[rc];
    }
#pragma unroll
    for (int nt = 0; nt < 4; ++nt) {
        int col = nt * 16 + colb;
        float wcol = W1[col];
#pragma unroll
        for (int rg = 0; rg < 4; ++rg) {
            int row = rowbase + rg;
            if (row < N)
                out[(size_t)row * 64 + col] = f2bf(dv[rg] * (acc[nt][rg] + vv[rg] * wcol));
        }
    }
}

// ---------------- fused aggregation + next-layer GEMM, bf16x2 gathers, 16-deep (R20 proven) ----------------
template <int IN, int ON, int EPI>
__global__ __launch_bounds__(256) void k_fagg(const unsigned short* __restrict__ gin,
                                              const int* __restrict__ rowoff,
                                              const int* __restrict__ colidx,
                                              const float* __restrict__ dinv,
                                              const float* __restrict__ bias,
                                              const float* __restrict__ W, int N,
                                              unsigned short* __restrict__ gout,
                                              float* __restrict__ gout1) {
    constexpr int GRP = IN / 2;
    constexpr int NPB = 256 / GRP;
    __shared__ float ws[IN * ON];
    __shared__ float hb[NPB][IN + 1];
    for (int j = threadIdx.x; j < IN * ON; j += 256) ws[j] = W[j];
    __syncthreads();
    int slot = threadIdx.x / GRP;
    int g = threadIdx.x % GRP;
    int v = blockIdx.x * NPB + slot;
    if (v >= N) return;
    const unsigned int* gin2 = (const unsigned int*)gin;
    int beg = rowoff[v], end = rowoff[v + 1];
    float dvv = dinv[v];
    float alo0 = 0.f, ahi0 = 0.f, alo1 = 0.f, ahi1 = 0.f;
    float alo2 = 0.f, ahi2 = 0.f, alo3 = 0.f, ahi3 = 0.f;
    int i = beg;
    for (; i + 16 <= end; i += 16) {            // 16 gathers in flight
        int u[16];
#pragma unroll
        for (int j = 0; j < 16; ++j) u[j] = colidx[i + j];
        unsigned int b[16];
#pragma unroll
        for (int j = 0; j < 16; ++j) b[j] = gin2[(size_t)u[j] * GRP + g];
#pragma unroll
        for (int j = 0; j < 16; j += 4) {
            alo0 += bflo(b[j]);     ahi0 += bfhi(b[j]);
            alo1 += bflo(b[j + 1]); ahi1 += bfhi(b[j + 1]);
            alo2 += bflo(b[j + 2]); ahi2 += bfhi(b[j + 2]);
            alo3 += bflo(b[j + 3]); ahi3 += bfhi(b[j + 3]);
        }
    }
    for (; i + 4 <= end; i += 4) {
        int u0 = colidx[i], u1 = colidx[i + 1], u2 = colidx[i + 2], u3 = colidx[i + 3];
        unsigned int b0 = gin2[(size_t)u0 * GRP + g];
        unsigned int b1 = gin2[(size_t)u1 * GRP + g];
        unsigned int b2 = gin2[(size_t)u2 * GRP + g];
        unsigned int b3 = gin2[(size_t)u3 * GRP + g];
        alo0 += bflo(b0); ahi0 += bfhi(b0);
        alo1 += bflo(b1); ahi1 += bfhi(b1);
        alo2 += bflo(b2); ahi2 += bfhi(b2);
        alo3 += bflo(b3); ahi3 += bfhi(b3);
    }
    for (; i < end; ++i) {
        unsigned int b0 = gin2[(size_t)colidx[i] * GRP + g];
        alo0 += bflo(b0); ahi0 += bfhi(b0);
    }
    float2 bs = ((const float2*)bias)[g];
    float tlo = dvv * ((alo0 + alo1) + (alo2 + alo3)) + bs.x;
    float thi = dvv * ((ahi0 + ahi1) + (ahi2 + ahi3)) + bs.y;
    float hlo = (EPI == 0) ? (tlo >= 0.f ? tlo : 0.01f * tlo) : (tlo >= 0.f ? 2.f * tlo : 1.01f * tlo);
    float hhi = (EPI == 0) ? (thi >= 0.f ? thi : 0.01f * thi) : (thi >= 0.f ? 2.f * thi : 1.01f * thi);
    hb[slot][2 * g] = hlo;
    hb[slot][2 * g + 1] = hhi;      // same-group (same-wave) LDS; hw-ordered
    if (ON == 32) {
        if (IN == 64) {             // GRP=32: lane g -> col g
            float acc = 0.f;
#pragma unroll
            for (int k = 0; k < 64; ++k) acc += hb[slot][k] * ws[k * 32 + g];
            gout[(size_t)v * 32 + g] = f2bf(dvv * acc);
        } else {                    // IN=32, GRP=16: lane g -> cols 2g,2g+1 (uint store)
            float a0 = 0.f, a1 = 0.f;
#pragma unroll
            for (int k = 0; k < 32; ++k) {
                float2 wv = *(const float2*)&ws[k * 32 + 2 * g];
                float h = hb[slot][k];
                a0 += h * wv.x;
                a1 += h * wv.y;
            }
            ((unsigned int*)gout)[(size_t)v * 16 + g] = pk_bf2(dvv * a0, dvv * a1);
        }
    } else {                        // ON==1, IN==32, GRP=16
        float p = hlo * ws[2 * g] + hhi * ws[2 * g + 1];
#pragma unroll
        for (int o = 8; o > 0; o >>= 1) p += __shfl_down(p, o, 16);
        if (g == 0) gout1[v] = dvv * p;
    }
}

// ---------------- tail: layer5 agg + fc1 partials (non-atomic) + last-block reduce/fc2 ----------------
__global__ __launch_bounds__(256) void k_tail(const float* __restrict__ g5,
                                              const int* __restrict__ rowoff,
                                              const int* __restrict__ colidx,
                                              const float* __restrict__ dinv,
                                              const float* __restrict__ b5,
                                              const float* __restrict__ fc1W,
                                              const float* __restrict__ fc1b,
                                              const float* __restrict__ fc2W,
                                              const float* __restrict__ fc2b,
                                              int N, int nblk,
                                              float* __restrict__ partials, int* __restrict__ done,
                                              float* __restrict__ outp) {
    __shared__ float vv[64];
    __shared__ float pacc[256];
    __shared__ float s1[128];
    __shared__ int lastf;
    int t = threadIdx.x;
    int r0 = blockIdx.x * 64;
    // phase A: 4 lanes/row, 8 gathers in flight per lane
    int rrow = r0 + (t >> 2);
    int q = t & 3;
    float p = 0.f;
    if (rrow < N) {
        int beg = rowoff[rrow], end = rowoff[rrow + 1];
        int i = beg + q;
        for (; i + 28 < end; i += 32) {
            int c[8];
#pragma unroll
            for (int j = 0; j < 8; ++j) c[j] = colidx[i + 4 * j];
            float gs = 0.f;
#pragma unroll
            for (int j = 0; j < 8; ++j) gs += g5[c[j]];
            p += gs;
        }
        for (; i < end; i += 4) p += g5[colidx[i]];
    }
    p += __shfl_xor(p, 1, 4);
    p += __shfl_xor(p, 2, 4);
    if (q == 0) {
        float val = 0.f;
        if (rrow < N) {
            float h = dinv[rrow] * p + b5[0];
            val = h >= 0.f ? h : 0.01f * h;
        }
        vv[t >> 2] = val;
    }
    __syncthreads();
    // phase B: fc1 partial over this block's 64 rows, 8 loads in flight
    int o = t & 127, half = t >> 7;
    float acc = 0.f;
    int rmax = min(64, N - r0);
    int j = half;
    for (; j + 14 < rmax; j += 16) {
        float wv[8], vr[8];
#pragma unroll
        for (int jj = 0; jj < 8; ++jj) {
            wv[jj] = fc1W[(size_t)(r0 + j + 2 * jj) * 128 + o];
            vr[jj] = vv[j + 2 * jj];
        }
#pragma unroll
        for (int jj = 0; jj < 8; ++jj) acc += vr[jj] * wv[jj];
    }
    for (; j < rmax; j += 2) acc += vv[j] * fc1W[(size_t)(r0 + j) * 128 + o];
    pacc[t] = acc;
    __syncthreads();
    if (t < 128) partials[(size_t)blockIdx.x * 128 + t] = pacc[t] + pacc[t + 128];
    __threadfence();                       // release: partials visible device-wide
    __syncthreads();
    if (t == 0) lastf = atomicAdd(done, 1);
    __syncthreads();
    if (lastf != nblk - 1) return;
    // ---- last block: reduce partials + fc1b/relu + fc2 + fc2b/relu ----
    __threadfence();                       // acquire: see all blocks' partials
    float acc2 = 0.f;
    int b = half;
    for (; b + 14 < nblk; b += 16) {       // 8 loads in flight
        float v8[8];
#pragma unroll
        for (int jj = 0; jj < 8; ++jj) v8[jj] = partials[(size_t)(b + 2 * jj) * 128 + o];
#pragma unroll
        for (int jj = 0; jj < 8; ++jj) acc2 += v8[jj];
    }
    for (; b < nblk; b += 2) acc2 += partials[(size_t)b * 128 + o];
    pacc[t] = acc2;
    __syncthreads();
    if (t < 128) {
        float h = pacc[t] + pacc[t + 128] + fc1b[t];
        s1[t] = h > 0.f ? h : 0.f;
    }
    __syncthreads();
    int c = t & 127, hh = t >> 7;
    float a2 = 0.f;
    int o0 = hh * 64;
    for (int oo = 0; oo < 64; oo += 8) {
        float wv[8];
#pragma unroll
        for (int jj = 0; jj < 8; ++jj) wv[jj] = fc2W[(o0 + oo + jj) * 128 + c];
#pragma unroll
        for (int jj = 0; jj < 8; ++jj) a2 += s1[o0 + oo + jj] * wv[jj];
    }
    pacc[t] = a2;
    __syncthreads();
    if (t < 128) {
        float r = pacc[t] + pacc[t + 128] + fc2b[t];
        outp[t] = r > 0.f ? r : 0.f;
    }
}

extern "C" void kernel_launch(void* const* d_in, const int* in_sizes, int n_in,
                              void* d_out, int out_size, void* d_ws, size_t ws_size,
                              hipStream_t stream) {
    const float* x = (const float*)d_in[0];
    const int* ei = (const int*)d_in[2];
    const float* emb = (const float*)d_in[3];
    const float* W1 = (const float*)d_in[4];
    const float* b1 = (const float*)d_in[5];
    const float* W2 = (const float*)d_in[6];
    const float* b2 = (const float*)d_in[7];
    const float* W3 = (const float*)d_in[8];
    const float* b3 = (const float*)d_in[9];
    const float* W4 = (const float*)d_in[10];
    const float* b4 = (const float*)d_in[11];
    const float* W5 = (const float*)d_in[12];
    const float* b5 = (const float*)d_in[13];
    const float* fc1W = (const float*)d_in[14];
    const float* fc1b = (const float*)d_in[15];
    const float* fc2W = (const float*)d_in[16];
    const float* fc2b = (const float*)d_in[17];

    int N = in_sizes[0] / FEATN;
    int E = in_sizes[2] / 2;
    int NNZ = E + N;
    int NBC = (N + CSZ - 1) / CSZ;
    int ntail = (N + 63) / 64;

    char* w = (char*)d_ws;
    auto alloc = [&](size_t bytes) {
        char* p = w;
        w += (bytes + 255) & ~(size_t)255;
        return p;
    };
    float* dinv   = (float*)alloc((size_t)N * 4);
    int*   rowoff = (int*)alloc((size_t)(N + 1) * 4);
    int*   colidx = (int*)alloc((size_t)NNZ * 4);
    float* valv   = (float*)alloc((size_t)N * 4);
    int*   gtails = (int*)alloc((size_t)NBC * 4);
    int*   doneb  = (int*)alloc(256);               // done counter (zeroed with gtails)
    unsigned int* bb = (unsigned int*)alloc((size_t)NBC * CAP2 * 4);
    unsigned short* Wf = (unsigned short*)alloc((size_t)KT_ALL * 4 * 64 * 8 * 2);
    unsigned short* g1 = (unsigned short*)alloc((size_t)N * 64 * 2);
    unsigned short* g2 = (unsigned short*)alloc((size_t)N * 32 * 2);
    unsigned short* g3 = (unsigned short*)alloc((size_t)N * 32 * 2);
    float* g5     = (float*)alloc((size_t)N * 4);
    float* partials = (float*)alloc((size_t)ntail * 128 * 4);

    int nbp1 = (E + EPB - 1) / EPB;
    int nbv = (N + 255) / 256;
    int nprep = (KT_ALL * 4 * 64 * 8 + 255) / 256;

    // zero gtails + done counter (adjacent allocations) in one memset
    size_t zlen = (size_t)((char*)doneb - (char*)gtails) + 256;
    hipMemsetAsync(gtails, 0, zlen, stream);

    k_p1v<<<nbp1 + nbv + nprep, 256, 0, stream>>>(ei, E, N, nbp1, nbv, gtails, bb,
                                                  x, emb, valv, W1, Wf);
    k_p2<<<NBC, 256, 0, stream>>>(bb, gtails, NBC, N, rowoff, dinv, colidx);

    k_gemm1m<<<(N + 63) / 64, 256, 0, stream>>>(x, Wf, W1, valv, dinv, N, g1);

    // layer1 agg + W2 ; layer2 agg + W3 ; layer3 agg(+res) + W4 ; layer4 agg(+res) + W5
    k_fagg<64, 32, 0><<<(N + 7) / 8, 256, 0, stream>>>(g1, rowoff, colidx, dinv, b1, W2, N, g2, nullptr);
    k_fagg<32, 32, 0><<<(N + 15) / 16, 256, 0, stream>>>(g2, rowoff, colidx, dinv, b2, W3, N, g3, nullptr);
    k_fagg<32, 32, 1><<<(N + 15) / 16, 256, 0, stream>>>(g3, rowoff, colidx, dinv, b3, W4, N, g2, nullptr);
    k_fagg<32, 1, 1><<<(N + 15) / 16, 256, 0, stream>>>(g2, rowoff, colidx, dinv, b4, W5, N, nullptr, g5);

    k_tail<<<ntail, 256, 0, stream>>>(g5, rowoff, colidx, dinv, b5, fc1W, fc1b, fc2W, fc2b,
                                      N, ntail, partials, doneb, (float*)d_out);
}

// Round 24
// 178.777 us; speedup vs baseline: 1.2545x; 1.2545x over previous
//
#include <hip/hip_runtime.h>
#include <hip/hip_bf16.h>

#define FEATN 898
#define EMBD 128
#define KT_FULL 28          // 28 full k-tiles of 32 (896); tile 28 (k=896..897) on register path
#define KT_ALL 29           // padded tiles in Wfrag
#define CH 2                // k-tiles per async-staged chunk (64 f32 cols)
#define NCHUNK 14           // KT_FULL / CH
#define CBITS 8
#define CSZ 256             // nodes per coarse bucket
#define CAP2 12288          // per-bucket capacity (mean ~8183, +45 sigma)
#define EPB 4096            // edges per p1 block

typedef __bf16 bf16x8 __attribute__((ext_vector_type(8)));
typedef float f32x4 __attribute__((ext_vector_type(4)));
typedef unsigned short ushort8 __attribute__((ext_vector_type(8)));

__device__ inline unsigned short f2bf(float f) {
    unsigned int u = __float_as_uint(f);
    unsigned int r = u + 0x7fffu + ((u >> 16) & 1u);   // RNE
    return (unsigned short)(r >> 16);
}
__device__ inline float bflo(unsigned int u) {
    return __uint_as_float(u << 16);
}
__device__ inline float bfhi(unsigned int u) {
    return __uint_as_float(u & 0xFFFF0000u);
}
__device__ inline unsigned int pk_bf2(float a, float b) {
    __hip_bfloat162 h = __float22bfloat162_rn(make_float2(a, b));
    unsigned int r;
    __builtin_memcpy(&r, &h, 4);
    return r;
}
// async global->LDS DMA, 16B/lane: dest = lds base (wave-uniform) + lane*16; src per-lane
__device__ inline void gl16(const void* g, void* l) {
    __builtin_amdgcn_global_load_lds((const __attribute__((address_space(1))) unsigned int*)g,
                                     (__attribute__((address_space(3))) unsigned int*)l,
                                     16, 0, 0);
}

// ---------------- p1 + valprep merged: blocks [0,nbp1) sort edges; rest do valv/Wf prep ----------------
__global__ __launch_bounds__(256) void k_p1v(const int* __restrict__ ei, int E, int N, int nbp1, int nbv,
                                             int* __restrict__ gtails, unsigned int* __restrict__ bb,
                                             const float* __restrict__ x, const float* __restrict__ emb,
                                             float* __restrict__ valv,
                                             const float* __restrict__ W1, unsigned short* __restrict__ Wf) {
    int t = threadIdx.x;
    if ((int)blockIdx.x >= nbp1) {
        int vb = (int)blockIdx.x - nbp1;
        if (vb < nbv) {                           // valv: feat[i][0] = emb[poi[i>>7]][i&127]
            int i = vb * 256 + t;
            if (i < N) {
                int r = i >> 7;
                int poi = (int)x[(size_t)r * FEATN];
                poi = min(max(poi, 0), N - 1);
                valv[i] = emb[(size_t)poi * EMBD + (i & 127)];
            }
        } else {                                   // Wfrag prep
            int id = (vb - nbv) * 256 + t;
            if (id < KT_ALL * 4 * 64 * 8) {
                int e = id & 7;
                int l = (id >> 3) & 63;
                int nt = (id >> 9) & 3;
                int kt = id >> 11;
                int k = kt * 32 + (l >> 4) * 8 + e;
                int n = nt * 16 + (l & 15);
                float v = (k < FEATN) ? W1[(size_t)k * 64 + n] : 0.f;
                Wf[id] = f2bf(v);
            }
        }
        return;
    }
    // ---- p1 body: in-LDS counting sort per block -> coalesced global runs ----
    __shared__ unsigned int stash[EPB];       // 16 KB, sorted by bucket
    __shared__ int hist[256], loff[256], gbase[256], lcur[256], sc[256];
    __shared__ int anyf;
    hist[t] = 0;
    if (t == 0) anyf = 0;
    __syncthreads();
    if (ei[2 * t + 1] != 0) atomicOr(&anyf, 1);   // int64 layout => hi words all zero
    __syncthreads();
    int f = anyf;                                  // 1 = int32 layout, 0 = int64 lo/hi pairs
    int e0 = blockIdx.x * EPB;
#pragma unroll
    for (int i = 0; i < EPB / 256; ++i) {
        int e = e0 + i * 256 + t;
        if (e < E) {
            int d = f ? ei[(size_t)E + e] : ei[2 * ((size_t)E + e)];
            d = min(max(d, 0), N - 1);
            atomicAdd(&hist[d >> CBITS], 1);
        }
    }
    __syncthreads();
    int v = hist[t];
    sc[t] = v;
    __syncthreads();
    for (int o = 1; o < 256; o <<= 1) {
        int x_ = (t >= o) ? sc[t - o] : 0;
        __syncthreads();
        sc[t] += x_;
        __syncthreads();
    }
    loff[t] = sc[t] - v;
    lcur[t] = sc[t] - v;
    gbase[t] = (v > 0) ? atomicAdd(&gtails[t], v) : 0;
    __syncthreads();
#pragma unroll
    for (int i = 0; i < EPB / 256; ++i) {
        int e = e0 + i * 256 + t;
        if (e < E) {
            int s_ = f ? ei[e] : ei[2 * (size_t)e];
            int d = f ? ei[(size_t)E + e] : ei[2 * ((size_t)E + e)];
            s_ = min(max(s_, 0), N - 1);
            d = min(max(d, 0), N - 1);
            int p = atomicAdd(&lcur[d >> CBITS], 1);
            stash[p] = ((unsigned)s_ << 16) | (unsigned)d;
        }
    }
    __syncthreads();
    int T = min(EPB, E - e0);
    for (int i = t; i < T; i += 256) {
        unsigned int u = stash[i];
        int d = (int)(u & 0xFFFFu);
        int c = d >> CBITS;
        int pos = gbase[c] + (i - loff[c]);
        if (pos < CAP2)
            bb[(size_t)c * CAP2 + pos] = ((u >> 16) << CBITS) | (unsigned)(d & (CSZ - 1));
    }
}

// ---------------- p2 (+inline bucket-offset scan): per-bucket CSR build in LDS ----------------
__global__ __launch_bounds__(256) void k_p2(const unsigned int* __restrict__ bb,
                                            const int* __restrict__ gtails, int nbc,
                                            int N, int* __restrict__ rowoff, float* __restrict__ dinv,
                                            int* __restrict__ colidx) {
    __shared__ unsigned int stash[CAP2];     // 48 KB
    __shared__ int hist[CSZ], curs[CSZ], sc[CSZ], tta[CSZ];
    int b = blockIdx.x;
    int t = threadIdx.x;
    int tot = 0;
    if (t < nbc) tot = min(gtails[t], CAP2) + min(CSZ, N - t * CSZ);
    tta[t] = tot;
    sc[t] = tot;
    __syncthreads();
    for (int o = 1; o < 256; o <<= 1) {
        int x_ = (t >= o) ? sc[t - o] : 0;
        __syncthreads();
        sc[t] += x_;
        __syncthreads();
    }
    if (b == nbc - 1 && t == 0) rowoff[N] = sc[nbc - 1];   // grand total
    int base = sc[b] - tta[b];
    __syncthreads();
    int node0 = b * CSZ;
    int nbn = min(CSZ, N - node0);
    int T = min(gtails[b], CAP2);
    hist[t] = 0;
    __syncthreads();
    for (int i = t; i < T; i += 256) {
        unsigned int u = bb[(size_t)b * CAP2 + i];
        stash[i] = u;
        atomicAdd(&hist[u & (CSZ - 1)], 1);
    }
    __syncthreads();
    int v = (t < nbn) ? hist[t] + 1 : 0;
    sc[t] = v;
    __syncthreads();
    for (int o = 1; o < 256; o <<= 1) {
        int x_ = (t >= o) ? sc[t - o] : 0;
        __syncthreads();
        sc[t] += x_;
        __syncthreads();
    }
    if (t < nbn) {
        int node = node0 + t;
        int ex = sc[t] - v;
        rowoff[node] = base + ex;
        dinv[node] = rsqrtf((float)(hist[t] + 1));
        colidx[base + ex] = node;            // self loop first
        curs[t] = ex + 1;
    }
    __syncthreads();
    for (int i = t; i < T; i += 256) {
        unsigned int u = stash[i];
        int slot = atomicAdd(&curs[u & (CSZ - 1)], 1);
        colidx[base + slot] = (int)(u >> CBITS);
    }
}

// ---------------- GEMM1 via MFMA: row-major-linear x staging (4 segments/DMA), dbuf ----------------
__global__ __launch_bounds__(256, 3) void k_gemm1m(const float* __restrict__ x,
                                                   const unsigned short* __restrict__ Wf,
                                                   const float* __restrict__ W1,
                                                   const float* __restrict__ valv,
                                                   const float* __restrict__ dinv, int N,
                                                   unsigned short* __restrict__ out) {
    __shared__ float xl[2][64 * 64];           // [buf][row*64 + col]  32 KB
    __shared__ ushort8 wlds[2][CH * 4 * 64];   // [buf][granule]       16 KB
    int t = threadIdx.x;
    int w = t >> 6;
    int l = t & 63;
    int r0 = blockIdx.x * 64;
    int kg = l >> 4;
    const ushort8* wfg = (const ushort8*)Wf;

    auto STAGE = [&](int c, int buf) {
        int c64 = c * 64;
#pragma unroll
        for (int p = 0; p < 4; ++p) {
            int rr = w * 16 + p * 4 + (l >> 4);
            int rg = r0 + rr;
            if (rg >= N) rg = N - 1;
            gl16(x + (size_t)rg * FEATN + c64 + (l & 15) * 4, &xl[buf][(w * 16 + p * 4) * 64]);
        }
#pragma unroll
        for (int q = 0; q < 2; ++q) {
            int blkg = w * 2 + q;
            gl16(&wfg[(size_t)c * 512 + blkg * 64 + l], &wlds[buf][blkg * 64]);
        }
    };

    f32x4 acc[4];
#pragma unroll
    for (int nt = 0; nt < 4; ++nt) acc[nt] = (f32x4){0.f, 0.f, 0.f, 0.f};

    STAGE(0, 0);
    __syncthreads();
    for (int c = 0; c < NCHUNK; ++c) {
        int buf = c & 1;
        if (c + 1 < NCHUNK) STAGE(c + 1, buf ^ 1);
#pragma unroll
        for (int kt = 0; kt < CH; ++kt) {
            const float* xr = &xl[buf][(w * 16 + (l & 15)) * 64 + kt * 32 + kg * 8];
            f32x4 lo = *(const f32x4*)xr;
            f32x4 hi = *(const f32x4*)(xr + 4);
            if (c == 0 && kt == 0 && kg == 0) lo.x = 0.f;   // zero POI-id col
            ushort8 u;
            unsigned int p0 = pk_bf2(lo.x, lo.y), p1 = pk_bf2(lo.z, lo.w);
            unsigned int p2 = pk_bf2(hi.x, hi.y), p3 = pk_bf2(hi.z, hi.w);
            u[0] = (unsigned short)p0; u[1] = (unsigned short)(p0 >> 16);
            u[2] = (unsigned short)p1; u[3] = (unsigned short)(p1 >> 16);
            u[4] = (unsigned short)p2; u[5] = (unsigned short)(p2 >> 16);
            u[6] = (unsigned short)p3; u[7] = (unsigned short)(p3 >> 16);
            bf16x8 a;
            __builtin_memcpy(&a, &u, 16);
#pragma unroll
            for (int nt = 0; nt < 4; ++nt) {
                bf16x8 b;
                ushort8 ub = wlds[buf][(kt * 4 + nt) * 64 + l];
                __builtin_memcpy(&b, &ub, 16);
                acc[nt] = __builtin_amdgcn_mfma_f32_16x16x32_bf16(a, b, acc[nt], 0, 0, 0);
            }
        }
        __syncthreads();
    }
    {   // tail k-tile (k=896..897)
        int rA = r0 + w * 16 + (l & 15);
        int rC = (rA < N) ? rA : (N - 1);
        ushort8 u = (ushort8)0;
        if (kg == 0) {
            float2 q = *(const float2*)(x + (size_t)rC * FEATN + 896);
            u[0] = f2bf(q.x);
            u[1] = f2bf(q.y);
        }
        bf16x8 a;
        __builtin_memcpy(&a, &u, 16);
#pragma unroll
        for (int nt = 0; nt < 4; ++nt) {
            bf16x8 b;
            ushort8 ub = wfg[(KT_FULL * 4 + nt) * 64 + l];
            __builtin_memcpy(&b, &ub, 16);
            acc[nt] = __builtin_amdgcn_mfma_f32_16x16x32_bf16(a, b, acc[nt], 0, 0, 0);
        }
    }

    int colb = l & 15;
    int rquad = l >> 4;
    int rowbase = r0 + w * 16 + rquad * 4;
    float dv[4], vv[4];
#pragma unroll
    for (int rg = 0; rg < 4; ++rg) {
        int row = rowbase + rg;
        int rc = (row < N) ? row : (N - 1);
        dv[rg] = dinv[rc];
        vv[rg] = valv[rc];
    }
#pragma unroll
    for (int nt = 0; nt < 4; ++nt) {
        int col = nt * 16 + colb;
        float wcol = W1[col];
#pragma unroll
        for (int rg = 0; rg < 4; ++rg) {
            int row = rowbase + rg;
            if (row < N)
                out[(size_t)row * 64 + col] = f2bf(dv[rg] * (acc[nt][rg] + vv[rg] * wcol));
        }
    }
}

// ---------------- fused aggregation + next-layer GEMM, bf16x2 gathers, 16-deep (R20 proven) ----------------
template <int IN, int ON, int EPI>
__global__ __launch_bounds__(256) void k_fagg(const unsigned short* __restrict__ gin,
                                              const int* __restrict__ rowoff,
                                              const int* __restrict__ colidx,
                                              const float* __restrict__ dinv,
                                              const float* __restrict__ bias,
                                              const float* __restrict__ W, int N,
                                              unsigned short* __restrict__ gout,
                                              float* __restrict__ gout1) {
    constexpr int GRP = IN / 2;
    constexpr int NPB = 256 / GRP;
    __shared__ float ws[IN * ON];
    __shared__ float hb[NPB][IN + 1];
    for (int j = threadIdx.x; j < IN * ON; j += 256) ws[j] = W[j];
    __syncthreads();
    int slot = threadIdx.x / GRP;
    int g = threadIdx.x % GRP;
    int v = blockIdx.x * NPB + slot;
    if (v >= N) return;
    const unsigned int* gin2 = (const unsigned int*)gin;
    int beg = rowoff[v], end = rowoff[v + 1];
    float dvv = dinv[v];
    float alo0 = 0.f, ahi0 = 0.f, alo1 = 0.f, ahi1 = 0.f;
    float alo2 = 0.f, ahi2 = 0.f, alo3 = 0.f, ahi3 = 0.f;
    int i = beg;
    for (; i + 16 <= end; i += 16) {            // 16 gathers in flight
        int u[16];
#pragma unroll
        for (int j = 0; j < 16; ++j) u[j] = colidx[i + j];
        unsigned int b[16];
#pragma unroll
        for (int j = 0; j < 16; ++j) b[j] = gin2[(size_t)u[j] * GRP + g];
#pragma unroll
        for (int j = 0; j < 16; j += 4) {
            alo0 += bflo(b[j]);     ahi0 += bfhi(b[j]);
            alo1 += bflo(b[j + 1]); ahi1 += bfhi(b[j + 1]);
            alo2 += bflo(b[j + 2]); ahi2 += bfhi(b[j + 2]);
            alo3 += bflo(b[j + 3]); ahi3 += bfhi(b[j + 3]);
        }
    }
    for (; i + 4 <= end; i += 4) {
        int u0 = colidx[i], u1 = colidx[i + 1], u2 = colidx[i + 2], u3 = colidx[i + 3];
        unsigned int b0 = gin2[(size_t)u0 * GRP + g];
        unsigned int b1 = gin2[(size_t)u1 * GRP + g];
        unsigned int b2 = gin2[(size_t)u2 * GRP + g];
        unsigned int b3 = gin2[(size_t)u3 * GRP + g];
        alo0 += bflo(b0); ahi0 += bfhi(b0);
        alo1 += bflo(b1); ahi1 += bfhi(b1);
        alo2 += bflo(b2); ahi2 += bfhi(b2);
        alo3 += bflo(b3); ahi3 += bfhi(b3);
    }
    for (; i < end; ++i) {
        unsigned int b0 = gin2[(size_t)colidx[i] * GRP + g];
        alo0 += bflo(b0); ahi0 += bfhi(b0);
    }
    float2 bs = ((const float2*)bias)[g];
    float tlo = dvv * ((alo0 + alo1) + (alo2 + alo3)) + bs.x;
    float thi = dvv * ((ahi0 + ahi1) + (ahi2 + ahi3)) + bs.y;
    float hlo = (EPI == 0) ? (tlo >= 0.f ? tlo : 0.01f * tlo) : (tlo >= 0.f ? 2.f * tlo : 1.01f * tlo);
    float hhi = (EPI == 0) ? (thi >= 0.f ? thi : 0.01f * thi) : (thi >= 0.f ? 2.f * thi : 1.01f * thi);
    hb[slot][2 * g] = hlo;
    hb[slot][2 * g + 1] = hhi;      // same-group (same-wave) LDS; hw-ordered
    if (ON == 32) {
        if (IN == 64) {             // GRP=32: lane g -> col g
            float acc = 0.f;
#pragma unroll
            for (int k = 0; k < 64; ++k) acc += hb[slot][k] * ws[k * 32 + g];
            gout[(size_t)v * 32 + g] = f2bf(dvv * acc);
        } else {                    // IN=32, GRP=16: lane g -> cols 2g,2g+1 (uint store)
            float a0 = 0.f, a1 = 0.f;
#pragma unroll
            for (int k = 0; k < 32; ++k) {
                float2 wv = *(const float2*)&ws[k * 32 + 2 * g];
                float h = hb[slot][k];
                a0 += h * wv.x;
                a1 += h * wv.y;
            }
            ((unsigned int*)gout)[(size_t)v * 16 + g] = pk_bf2(dvv * a0, dvv * a1);
        }
    } else {                        // ON==1, IN==32, GRP=16
        float p = hlo * ws[2 * g] + hhi * ws[2 * g + 1];
#pragma unroll
        for (int o = 8; o > 0; o >>= 1) p += __shfl_down(p, o, 16);
        if (g == 0) gout1[v] = dvv * p;
    }
}

// ---------------- tail: layer5 agg + fc1 partial -> NON-ATOMIC per-block partials ----------------
__global__ __launch_bounds__(256) void k_tail(const float* __restrict__ g5,
                                              const int* __restrict__ rowoff,
                                              const int* __restrict__ colidx,
                                              const float* __restrict__ dinv,
                                              const float* __restrict__ b5,
                                              const float* __restrict__ fc1W,
                                              int N, float* __restrict__ partials) {
    __shared__ float vv[64];
    __shared__ float pacc[256];
    int t = threadIdx.x;
    int r0 = blockIdx.x * 64;
    // phase A: 4 lanes/row, 8 gathers in flight per lane
    int rrow = r0 + (t >> 2);
    int q = t & 3;
    float p = 0.f;
    if (rrow < N) {
        int beg = rowoff[rrow], end = rowoff[rrow + 1];
        int i = beg + q;
        for (; i + 28 < end; i += 32) {
            int c[8];
#pragma unroll
            for (int j = 0; j < 8; ++j) c[j] = colidx[i + 4 * j];
            float gs = 0.f;
#pragma unroll
            for (int j = 0; j < 8; ++j) gs += g5[c[j]];
            p += gs;
        }
        for (; i < end; i += 4) p += g5[colidx[i]];
    }
    p += __shfl_xor(p, 1, 4);
    p += __shfl_xor(p, 2, 4);
    if (q == 0) {
        float val = 0.f;
        if (rrow < N) {
            float h = dinv[rrow] * p + b5[0];
            val = h >= 0.f ? h : 0.01f * h;
        }
        vv[t >> 2] = val;
    }
    __syncthreads();
    // phase B: fc1 partial over this block's 64 rows, 8 loads in flight
    int o = t & 127, half = t >> 7;
    float acc = 0.f;
    int rmax = min(64, N - r0);
    int j = half;
    for (; j + 14 < rmax; j += 16) {
        float wv[8], vr[8];
#pragma unroll
        for (int jj = 0; jj < 8; ++jj) {
            wv[jj] = fc1W[(size_t)(r0 + j + 2 * jj) * 128 + o];
            vr[jj] = vv[j + 2 * jj];
        }
#pragma unroll
        for (int jj = 0; jj < 8; ++jj) acc += vr[jj] * wv[jj];
    }
    for (; j < rmax; j += 2) acc += vv[j] * fc1W[(size_t)(r0 + j) * 128 + o];
    pacc[t] = acc;
    __syncthreads();
    if (t < 128) partials[(size_t)blockIdx.x * 128 + t] = pacc[t] + pacc[t + 128];
}

// ---------------- fin: reduce partials + fc1b/relu + fc2 + fc2b/relu (1 block) ----------------
__global__ __launch_bounds__(256) void k_fin(const float* __restrict__ partials, int nblk,
                                             const float* __restrict__ fc1b,
                                             const float* __restrict__ fc2W,
                                             const float* __restrict__ fc2b,
                                             float* __restrict__ outp) {
    __shared__ float s1[128];
    __shared__ float pacc[256];
    int t = threadIdx.x;
    int o = t & 127, half = t >> 7;
    float acc = 0.f;
    int b = half;
    for (; b + 14 < nblk; b += 16) {             // 8 loads in flight
        float v[8];
#pragma unroll
        for (int j = 0; j < 8; ++j) v[j] = partials[(size_t)(b + 2 * j) * 128 + o];
#pragma unroll
        for (int j = 0; j < 8; ++j) acc += v[j];
    }
    for (; b < nblk; b += 2) acc += partials[(size_t)b * 128 + o];
    pacc[t] = acc;
    __syncthreads();
    if (t < 128) {
        float h = pacc[t] + pacc[t + 128] + fc1b[t];
        s1[t] = h > 0.f ? h : 0.f;
    }
    __syncthreads();
    // fc2: 256 threads, col c = t&127, row-half hh
    int c = t & 127, hh = t >> 7;
    float a2 = 0.f;
    int o0 = hh * 64;
    for (int oo = 0; oo < 64; oo += 8) {
        float wv[8];
#pragma unroll
        for (int jj = 0; jj < 8; ++jj) wv[jj] = fc2W[(o0 + oo + jj) * 128 + c];
#pragma unroll
        for (int jj = 0; jj < 8; ++jj) a2 += s1[o0 + oo + jj] * wv[jj];
    }
    pacc[t] = a2;
    __syncthreads();
    if (t < 128) {
        float r = pacc[t] + pacc[t + 128] + fc2b[t];
        outp[t] = r > 0.f ? r : 0.f;
    }
}

extern "C" void kernel_launch(void* const* d_in, const int* in_sizes, int n_in,
                              void* d_out, int out_size, void* d_ws, size_t ws_size,
                              hipStream_t stream) {
    const float* x = (const float*)d_in[0];
    const int* ei = (const int*)d_in[2];
    const float* emb = (const float*)d_in[3];
    const float* W1 = (const float*)d_in[4];
    const float* b1 = (const float*)d_in[5];
    const float* W2 = (const float*)d_in[6];
    const float* b2 = (const float*)d_in[7];
    const float* W3 = (const float*)d_in[8];
    const float* b3 = (const float*)d_in[9];
    const float* W4 = (const float*)d_in[10];
    const float* b4 = (const float*)d_in[11];
    const float* W5 = (const float*)d_in[12];
    const float* b5 = (const float*)d_in[13];
    const float* fc1W = (const float*)d_in[14];
    const float* fc1b = (const float*)d_in[15];
    const float* fc2W = (const float*)d_in[16];
    const float* fc2b = (const float*)d_in[17];

    int N = in_sizes[0] / FEATN;
    int E = in_sizes[2] / 2;
    int NNZ = E + N;
    int NBC = (N + CSZ - 1) / CSZ;
    int ntail = (N + 63) / 64;

    char* w = (char*)d_ws;
    auto alloc = [&](size_t bytes) {
        char* p = w;
        w += (bytes + 255) & ~(size_t)255;
        return p;
    };
    float* dinv   = (float*)alloc((size_t)N * 4);
    int*   rowoff = (int*)alloc((size_t)(N + 1) * 4);
    int*   colidx = (int*)alloc((size_t)NNZ * 4);
    float* valv   = (float*)alloc((size_t)N * 4);
    int*   gtails = (int*)alloc((size_t)NBC * 4);
    unsigned int* bb = (unsigned int*)alloc((size_t)NBC * CAP2 * 4);
    unsigned short* Wf = (unsigned short*)alloc((size_t)KT_ALL * 4 * 64 * 8 * 2);
    unsigned short* g1 = (unsigned short*)alloc((size_t)N * 64 * 2);
    unsigned short* g2 = (unsigned short*)alloc((size_t)N * 32 * 2);
    unsigned short* g3 = (unsigned short*)alloc((size_t)N * 32 * 2);
    float* g5     = (float*)alloc((size_t)N * 4);
    float* partials = (float*)alloc((size_t)ntail * 128 * 4);

    int nbp1 = (E + EPB - 1) / EPB;
    int nbv = (N + 255) / 256;
    int nprep = (KT_ALL * 4 * 64 * 8 + 255) / 256;

    hipMemsetAsync(gtails, 0, (size_t)NBC * 4, stream);

    k_p1v<<<nbp1 + nbv + nprep, 256, 0, stream>>>(ei, E, N, nbp1, nbv, gtails, bb,
                                                  x, emb, valv, W1, Wf);
    k_p2<<<NBC, 256, 0, stream>>>(bb, gtails, NBC, N, rowoff, dinv, colidx);

    k_gemm1m<<<(N + 63) / 64, 256, 0, stream>>>(x, Wf, W1, valv, dinv, N, g1);

    // layer1 agg + W2 ; layer2 agg + W3 ; layer3 agg(+res) + W4 ; layer4 agg(+res) + W5
    k_fagg<64, 32, 0><<<(N + 7) / 8, 256, 0, stream>>>(g1, rowoff, colidx, dinv, b1, W2, N, g2, nullptr);
    k_fagg<32, 32, 0><<<(N + 15) / 16, 256, 0, stream>>>(g2, rowoff, colidx, dinv, b2, W3, N, g3, nullptr);
    k_fagg<32, 32, 1><<<(N + 15) / 16, 256, 0, stream>>>(g3, rowoff, colidx, dinv, b3, W4, N, g2, nullptr);
    k_fagg<32, 1, 1><<<(N + 15) / 16, 256, 0, stream>>>(g2, rowoff, colidx, dinv, b4, W5, N, nullptr, g5);

    k_tail<<<ntail, 256, 0, stream>>>(g5, rowoff, colidx, dinv, b5, fc1W, N, partials);
    k_fin<<<1, 256, 0, stream>>>(partials, ntail, fc1b, fc2W, fc2b, (float*)d_out);
}